// Round 1
// baseline (191.828 us; speedup 1.0000x reference)
//
#include <hip/hip_runtime.h>

typedef _Float16 half8  __attribute__((ext_vector_type(8)));
typedef _Float16 half4v __attribute__((ext_vector_type(4)));
typedef float    floatx4 __attribute__((ext_vector_type(4)));

// pooled ws layout: [128][16][11] fp32 = 22528 floats
__global__ __launch_bounds__(256) void knrm_zero(float* __restrict__ p) {
    p[blockIdx.x * 256 + threadIdx.x] = 0.0f;
}

__global__ __launch_bounds__(256) void knrm_main(
    const int*   __restrict__ queries,    // 128 x 16
    const int*   __restrict__ documents,  // 128 x 2048
    const float* __restrict__ emb,        // 100000 x 128
    float*       __restrict__ pooled)     // 128 x 16 x 11 (atomic accum)
{
    __shared__ __align__(16) _Float16 Qs[16][136];  // +8 halfs pad: fragment reads 2-way (free)
    __shared__ __align__(16) _Float16 Ds[64][136];
    __shared__ float qn_s[16];
    __shared__ float dn_s[64];
    __shared__ float pooled_s[176];

    const int tid  = threadIdx.x;
    const int b    = blockIdx.x >> 3;
    const int tok0 = (blockIdx.x & 7) * 256;

    // ---- stage Q (16 rows x 128 e), fp32 norms, fp16 into LDS ----
    {
        const int row = tid >> 4, sub = tid & 15;
        const int qi = queries[b * 16 + row];
        const float4* src = (const float4*)(emb + (size_t)qi * 128 + sub * 8);
        float4 v0 = src[0], v1 = src[1];
        half8 h;
        h[0] = (_Float16)v0.x; h[1] = (_Float16)v0.y;
        h[2] = (_Float16)v0.z; h[3] = (_Float16)v0.w;
        h[4] = (_Float16)v1.x; h[5] = (_Float16)v1.y;
        h[6] = (_Float16)v1.z; h[7] = (_Float16)v1.w;
        *(half8*)&Qs[row][sub * 8] = h;
        float ns = v0.x*v0.x + v0.y*v0.y + v0.z*v0.z + v0.w*v0.w
                 + v1.x*v1.x + v1.y*v1.y + v1.z*v1.z + v1.w*v1.w;
        ns += __shfl_xor(ns, 1); ns += __shfl_xor(ns, 2);
        ns += __shfl_xor(ns, 4); ns += __shfl_xor(ns, 8);
        if (sub == 0) qn_s[row] = sqrtf(ns);
    }
    if (tid < 176) pooled_s[tid] = 0.0f;
    __syncthreads();

    const int lane = tid & 63;
    const int wave = tid >> 6;
    const int col  = lane & 15;   // MFMA: A row m / B col n / C col
    const int quad = lane >> 4;   // MFMA: k-octet select / C row group

    // A fragments (queries) live in registers for the whole block
    half8 afrag[4];
#pragma unroll
    for (int c = 0; c < 4; ++c)
        afrag[c] = *(const half8*)&Qs[col][c * 32 + quad * 8];

    float pr[4][11];
#pragma unroll
    for (int r = 0; r < 4; ++r)
#pragma unroll
        for (int k = 0; k < 11; ++k) pr[r][k] = 0.0f;

    const int drow = tid >> 2, sub4 = tid & 3;   // 64 tokens x 4 threads each
    int idxs[4];
#pragma unroll
    for (int t = 0; t < 4; ++t)
        idxs[t] = documents[b * 2048 + tok0 + t * 64 + drow];

    for (int tile = 0; tile < 4; ++tile) {
        // ---- stage 64 doc tokens: gather fp32, convert fp16, fp32 norms ----
        {
            const float4* src = (const float4*)(emb + (size_t)idxs[tile] * 128 + sub4 * 32);
            float ns = 0.0f;
#pragma unroll
            for (int i = 0; i < 8; ++i) {
                float4 v = src[i];
                half4v h;
                h[0] = (_Float16)v.x; h[1] = (_Float16)v.y;
                h[2] = (_Float16)v.z; h[3] = (_Float16)v.w;
                *(half4v*)&Ds[drow][sub4 * 32 + i * 4] = h;
                ns += v.x*v.x + v.y*v.y + v.z*v.z + v.w*v.w;
            }
            ns += __shfl_xor(ns, 1); ns += __shfl_xor(ns, 2);
            if (sub4 == 0) dn_s[drow] = sqrtf(ns);
        }
        __syncthreads();

        // ---- wave w computes 16q x 16tok sim tile for its token group ----
        floatx4 acc = {0.0f, 0.0f, 0.0f, 0.0f};
        const int trow = wave * 16 + col;
#pragma unroll
        for (int c = 0; c < 4; ++c) {
            half8 bfrag = *(const half8*)&Ds[trow][c * 32 + quad * 8];
            acc = __builtin_amdgcn_mfma_f32_16x16x32_f16(afrag[c], bfrag, acc, 0, 0, 0);
        }
        // C/D layout: col = lane&15 (token), row = quad*4 + r (query)
        const float dn = dn_s[trow];
#pragma unroll
        for (int r = 0; r < 4; ++r) {
            const float denom = qn_s[quad * 4 + r] * dn + 1e-8f;
            const float sim = acc[r] * __builtin_amdgcn_rcpf(denom);
#pragma unroll
            for (int k = 0; k < 11; ++k) {
                const float t = sim - (-1.0f + 0.2f * (float)k);
                // exp(-t^2/(2*0.1^2)) = exp2(-50*log2(e) * t^2)
                pr[r][k] += __builtin_amdgcn_exp2f(t * t * -72.13475204444817f);
            }
        }
        __syncthreads();   // Ds/dn_s reads done before next restage
    }

    // ---- block-level reduction, then 176 global atomics ----
#pragma unroll
    for (int r = 0; r < 4; ++r)
#pragma unroll
        for (int k = 0; k < 11; ++k)
            atomicAdd(&pooled_s[(quad * 4 + r) * 11 + k], pr[r][k]);
    __syncthreads();
    if (tid < 176) atomicAdd(&pooled[b * 176 + tid], pooled_s[tid]);
}

__global__ __launch_bounds__(128) void knrm_final(
    const float* __restrict__ pooled,
    const float* __restrict__ W,
    const float* __restrict__ bias,
    float*       __restrict__ out)
{
    const int b = threadIdx.x;   // one block of 128
    float acc = bias[0];
#pragma unroll
    for (int k = 0; k < 11; ++k) {
        float s = 0.0f;
#pragma unroll
        for (int q = 0; q < 16; ++q)
            s += __builtin_amdgcn_logf(pooled[b * 176 + q * 11 + k]);  // log2
        acc += s * 0.69314718055994531f * W[k];                        // * ln2
    }
    out[b] = __builtin_amdgcn_rcpf(1.0f + __builtin_amdgcn_exp2f(acc * -1.4426950408889634f));
}

extern "C" void kernel_launch(void* const* d_in, const int* in_sizes, int n_in,
                              void* d_out, int out_size, void* d_ws, size_t ws_size,
                              hipStream_t stream) {
    const int*   queries   = (const int*)d_in[0];
    const int*   documents = (const int*)d_in[1];
    const float* emb       = (const float*)d_in[2];
    const float* W         = (const float*)d_in[3];
    const float* bias      = (const float*)d_in[4];
    float* out    = (float*)d_out;
    float* pooled = (float*)d_ws;   // 22528 floats = 88 KiB

    knrm_zero<<<88, 256, 0, stream>>>(pooled);                       // 88*256 == 22528
    knrm_main<<<1024, 256, 0, stream>>>(queries, documents, emb, pooled);
    knrm_final<<<1, 128, 0, stream>>>(pooled, W, bias, out);
}

// Round 2
// 185.889 us; speedup vs baseline: 1.0319x; 1.0319x over previous
//
#include <hip/hip_runtime.h>

typedef _Float16 half8  __attribute__((ext_vector_type(8)));
typedef float    floatx4 __attribute__((ext_vector_type(4)));

// pooled ws layout: [128][16][11] fp32 = 22528 floats
__global__ __launch_bounds__(256) void knrm_zero(float* __restrict__ p) {
    p[blockIdx.x * 256 + threadIdx.x] = 0.0f;
}

__global__ __launch_bounds__(256) void knrm_main(
    const int*   __restrict__ queries,    // 128 x 16
    const int*   __restrict__ documents,  // 128 x 2048
    const float* __restrict__ emb,        // 100000 x 128
    float*       __restrict__ pooled)     // 128 x 16 x 11 (atomic accum)
{
    __shared__ __align__(16) _Float16 Qs[16][136];  // pad: fragment reads 2-way (free)
    __shared__ float qn_s[16];
    __shared__ float pooled_s[176];

    const int tid  = threadIdx.x;
    const int b    = blockIdx.x >> 3;
    const int tok0 = (blockIdx.x & 7) * 256;

    // ---- stage Q (16 rows x 128 e): fp32 norms, fp16 into LDS ----
    {
        const int row = tid >> 4, sub = tid & 15;
        const int qi = queries[b * 16 + row];
        const float4* src = (const float4*)(emb + (size_t)qi * 128 + sub * 8);
        float4 v0 = src[0], v1 = src[1];
        half8 h;
        h[0] = (_Float16)v0.x; h[1] = (_Float16)v0.y;
        h[2] = (_Float16)v0.z; h[3] = (_Float16)v0.w;
        h[4] = (_Float16)v1.x; h[5] = (_Float16)v1.y;
        h[6] = (_Float16)v1.z; h[7] = (_Float16)v1.w;
        *(half8*)&Qs[row][sub * 8] = h;
        float ns = v0.x*v0.x + v0.y*v0.y + v0.z*v0.z + v0.w*v0.w
                 + v1.x*v1.x + v1.y*v1.y + v1.z*v1.z + v1.w*v1.w;
        ns += __shfl_xor(ns, 1); ns += __shfl_xor(ns, 2);
        ns += __shfl_xor(ns, 4); ns += __shfl_xor(ns, 8);
        if (sub == 0) qn_s[row] = sqrtf(ns);
    }
    if (tid < 176) pooled_s[tid] = 0.0f;
    __syncthreads();

    const int lane = tid & 63;
    const int wave = tid >> 6;
    const int col  = lane & 15;   // MFMA: A row m / B col n / C col
    const int quad = lane >> 4;   // MFMA: k-octet select / C row group

    // A fragments (queries) in registers for the whole block
    half8 afrag[4];
#pragma unroll
    for (int c = 0; c < 4; ++c)
        afrag[c] = *(const half8*)&Qs[col][c * 32 + quad * 8];

    float pr[4][11];
#pragma unroll
    for (int r = 0; r < 4; ++r)
#pragma unroll
        for (int k = 0; k < 11; ++k) pr[r][k] = 0.0f;

    // wave w handles tiles (j*4 + w), j=0..3; each lane gathers ITS B-fragment
    // (4 x 32B contiguous segments of token col's row) straight to registers.
    int idx[4];
#pragma unroll
    for (int j = 0; j < 4; ++j)
        idx[j] = documents[b * 2048 + tok0 + (j * 4 + wave) * 16 + col];

    float4 cur[8];
    {
        const float* rp = emb + (size_t)idx[0] * 128 + quad * 8;
#pragma unroll
        for (int c = 0; c < 4; ++c) {
            cur[2*c]   = *(const float4*)(rp + c * 32);
            cur[2*c+1] = *(const float4*)(rp + c * 32 + 4);
        }
    }

    for (int j = 0; j < 4; ++j) {
        float4 nxt[8];
        if (j < 3) {   // prefetch next tile while we compute this one
            const float* rp = emb + (size_t)idx[j + 1] * 128 + quad * 8;
#pragma unroll
            for (int c = 0; c < 4; ++c) {
                nxt[2*c]   = *(const float4*)(rp + c * 32);
                nxt[2*c+1] = *(const float4*)(rp + c * 32 + 4);
            }
        }

        // convert to fp16 fragments + fp32 norm
        half8 bf[4];
        float ns = 0.0f;
#pragma unroll
        for (int c = 0; c < 4; ++c) {
            float4 a = cur[2*c], d = cur[2*c+1];
            half8 h;
            h[0] = (_Float16)a.x; h[1] = (_Float16)a.y;
            h[2] = (_Float16)a.z; h[3] = (_Float16)a.w;
            h[4] = (_Float16)d.x; h[5] = (_Float16)d.y;
            h[6] = (_Float16)d.z; h[7] = (_Float16)d.w;
            bf[c] = h;
            ns += a.x*a.x + a.y*a.y + a.z*a.z + a.w*a.w
                + d.x*d.x + d.y*d.y + d.z*d.z + d.w*d.w;
        }
        ns += __shfl_xor(ns, 16);   // sum across the 4 quads holding this token
        ns += __shfl_xor(ns, 32);
        const float dn = sqrtf(ns);

        floatx4 acc = {0.0f, 0.0f, 0.0f, 0.0f};
#pragma unroll
        for (int c = 0; c < 4; ++c)
            acc = __builtin_amdgcn_mfma_f32_16x16x32_f16(afrag[c], bf[c], acc, 0, 0, 0);

        // C/D layout: col = lane&15 (token), row = quad*4 + r (query)
#pragma unroll
        for (int r = 0; r < 4; ++r) {
            const float denom = qn_s[quad * 4 + r] * dn + 1e-8f;
            const float sim = acc[r] * __builtin_amdgcn_rcpf(denom);
#pragma unroll
            for (int k = 0; k < 11; ++k) {
                const float t = sim - (-1.0f + 0.2f * (float)k);
                // exp(-t^2/(2*0.1^2)) = exp2(-50*log2(e) * t^2)
                pr[r][k] += __builtin_amdgcn_exp2f(t * t * -72.13475204444817f);
            }
        }

#pragma unroll
        for (int i = 0; i < 8; ++i) cur[i] = nxt[i];
    }

    // ---- block-level reduction, then 176 global atomics ----
#pragma unroll
    for (int r = 0; r < 4; ++r)
#pragma unroll
        for (int k = 0; k < 11; ++k)
            atomicAdd(&pooled_s[(quad * 4 + r) * 11 + k], pr[r][k]);
    __syncthreads();
    if (tid < 176) atomicAdd(&pooled[b * 176 + tid], pooled_s[tid]);
}

__global__ __launch_bounds__(128) void knrm_final(
    const float* __restrict__ pooled,
    const float* __restrict__ W,
    const float* __restrict__ bias,
    float*       __restrict__ out)
{
    const int b = threadIdx.x;   // one block of 128
    float acc = bias[0];
#pragma unroll
    for (int k = 0; k < 11; ++k) {
        float s = 0.0f;
#pragma unroll
        for (int q = 0; q < 16; ++q)
            s += __builtin_amdgcn_logf(pooled[b * 176 + q * 11 + k]);  // log2
        acc += s * 0.69314718055994531f * W[k];                        // * ln2
    }
    out[b] = __builtin_amdgcn_rcpf(1.0f + __builtin_amdgcn_exp2f(acc * -1.4426950408889634f));
}

extern "C" void kernel_launch(void* const* d_in, const int* in_sizes, int n_in,
                              void* d_out, int out_size, void* d_ws, size_t ws_size,
                              hipStream_t stream) {
    const int*   queries   = (const int*)d_in[0];
    const int*   documents = (const int*)d_in[1];
    const float* emb       = (const float*)d_in[2];
    const float* W         = (const float*)d_in[3];
    const float* bias      = (const float*)d_in[4];
    float* out    = (float*)d_out;
    float* pooled = (float*)d_ws;   // 22528 floats = 88 KiB

    knrm_zero<<<88, 256, 0, stream>>>(pooled);                       // 88*256 == 22528
    knrm_main<<<1024, 256, 0, stream>>>(queries, documents, emb, pooled);
    knrm_final<<<1, 128, 0, stream>>>(pooled, W, bias, out);
}